// Round 9
// baseline (186.245 us; speedup 1.0000x reference)
//
#include <hip/hip_runtime.h>
#include <stdint.h>

#define T_SEQ 2048
#define BATCH 2
#define DMODEL 1024
#define NH 16
#define DH 64
#define M_ROWS (T_SEQ * BATCH)   // 4096
#define N_QKV (3 * DMODEL)       // 3072

typedef unsigned short u16;
using bf16x8 = __attribute__((ext_vector_type(8))) __bf16;
using f32x4  = __attribute__((ext_vector_type(4))) float;

__device__ __forceinline__ u16 f2bf(float f) {
    union { float f; uint32_t u; } v; v.f = f;
    uint32_t r = v.u + 0x7fffu + ((v.u >> 16) & 1u);
    return (u16)(r >> 16);
}

__device__ __forceinline__ uint32_t pack2(float a, float b) {
    union { float f; uint32_t u; } x, y; x.f = a; y.f = b;
    return (x.u >> 16) | (y.u & 0xffff0000u);
}

__device__ __forceinline__ float bf2f(u16 u) {
    union { uint32_t u; float f; } v; v.u = (uint32_t)u << 16;
    return v.f;
}

// async 16B/lane global -> LDS; lds base wave-uniform, lane data lands at +lane*16
__device__ __forceinline__ void lds_load16(void* lds, const void* g) {
    auto lp = (__attribute__((address_space(3))) uint32_t*)(uint32_t)(uintptr_t)lds;
    auto gp = (const __attribute__((address_space(1))) uint32_t*)(uintptr_t)g;
    __builtin_amdgcn_global_load_lds(gp, lp, 16, 0, 0);
}

#define SCQ 0.18033688011112f    // (1/sqrt(64)) * log2(e), folded into Q at GEMM1

// ---------------- pre-pass (fused): x->bf16 + both weight transposes ---------
// blocks [0,4096): cvt4 over x (exactly 4096*256 float4 groups)
// blocks [4096,8192): 32x32 transpose tiles; gx<96 -> W_qkv, else W_out

__global__ void prep_kernel(const float* __restrict__ x, u16* __restrict__ xb,
                            const float* __restrict__ Wq, u16* __restrict__ oq,
                            const float* __restrict__ Wo, u16* __restrict__ oo) {
    __shared__ float t[32][33];
    if (blockIdx.x < 4096) {
        int i = blockIdx.x * 256 + threadIdx.x;
        float4 v = ((const float4*)x)[i];
        union { u16 u[4]; uint2 d; } o;
        o.u[0] = f2bf(v.x); o.u[1] = f2bf(v.y); o.u[2] = f2bf(v.z); o.u[3] = f2bf(v.w);
        ((uint2*)xb)[i] = o.d;
    } else {
        const int R = 1024;
        int bxx = blockIdx.x - 4096;
        int gx = bxx & 127, gy = bxx >> 7;
        const float* in; u16* out; int C, bx;
        if (gx < 96) { in = Wq; out = oq; C = 3072; bx = gx * 32; }
        else         { in = Wo; out = oo; C = 1024; bx = (gx - 96) * 32; }
        int by = gy * 32;
        int tx = threadIdx.x & 31, ty = threadIdx.x >> 5;
#pragma unroll
        for (int rr = 0; rr < 32; rr += 8)
            t[ty + rr][tx] = in[(size_t)(by + ty + rr) * C + bx + tx];
        __syncthreads();
#pragma unroll
        for (int rr = 0; rr < 32; rr += 8)
            out[(size_t)(bx + ty + rr) * R + by + tx] = f2bf(t[tx][ty + rr]);
    }
}

// ---------------- GEMM: A[M][K] bf16 rm, Bt[N][K] bf16 rm --------------------
// BM=128, BN=NF*32, BK=32, 4 waves (2x2), wave tile 64 x NF*16.
// Double-buffered global_load_lds staging: single barrier per K-iter,
// prefetch of k0+32 issued right after the barrier -> drain covered by MFMA.
// XOR chunk-swizzle: phys 16B chunk = logical ^ ((row>>1)&3)
// Session evidence, barrier domains/CU x work-per-barrier (non-monotonic):
//   1/CU NF=4 (r1,r2): bad   | 3/CU NF=4 (r0/r8): 45.3us MfmaUtil 22%
//   6/CU NF=2 (r7): bad (17%) | r9 trial: 2/CU NF=6 (24 MFMA/barrier, 20KB stage)

template<int EPI, int NF>
__global__ __launch_bounds__(256) void gemm_kernel(
    const u16* __restrict__ A, const u16* __restrict__ Bt,
    const float* __restrict__ bias,
    u16* __restrict__ outQ, u16* __restrict__ outK, u16* __restrict__ outV,
    float* __restrict__ outF,
    int M, int N, int K)
{
    __shared__ __align__(16) u16 lA[2][128 * 32];
    __shared__ __align__(16) u16 lB[2][NF * 32 * 32];

    const int tid  = threadIdx.x;
    const int bm   = blockIdx.y * 128;
    const int bn   = blockIdx.x * (NF * 32);
    const int lane = tid & 63;
    const int wid  = tid >> 6;
    const int wm   = (wid >> 1) * 64;
    const int wn   = (wid & 1) * (NF * 16);
    const int qr   = lane & 15;
    const int quad = lane >> 4;
    const int r4   = lane >> 2;
    const int c4   = (((lane & 3) ^ ((r4 >> 1) & 3))) * 8;
    const int sw   = (qr >> 1) & 3;

    f32x4 acc[4][NF];
#pragma unroll
    for (int i = 0; i < 4; i++)
#pragma unroll
        for (int j = 0; j < NF; j++) acc[i][j] = f32x4{0.f, 0.f, 0.f, 0.f};

    // prologue: stage k0 = 0 into buffer 0
#pragma unroll
    for (int cc = 0; cc < 2; cc++) {
        int c = wid + cc * 4;
        lds_load16(&lA[0][c * 512], &A[(size_t)(bm + 16 * c + r4) * K + c4]);
    }
#pragma unroll
    for (int c = wid; c < 2 * NF; c += 4)
        lds_load16(&lB[0][c * 512], &Bt[(size_t)(bn + 16 * c + r4) * K + c4]);

    int p = 0;
    for (int k0 = 0; k0 < K; k0 += 32, p ^= 1) {
        __syncthreads();                        // tile k0 landed; prev buffer reads done
        if (k0 + 32 < K) {                      // prefetch next tile into other buffer
            int nb = p ^ 1;
#pragma unroll
            for (int cc = 0; cc < 2; cc++) {
                int c = wid + cc * 4;
                lds_load16(&lA[nb][c * 512], &A[(size_t)(bm + 16 * c + r4) * K + k0 + 32 + c4]);
            }
#pragma unroll
            for (int c = wid; c < 2 * NF; c += 4)
                lds_load16(&lB[nb][c * 512], &Bt[(size_t)(bn + 16 * c + r4) * K + k0 + 32 + c4]);
        }

        bf16x8 af[4], bfr[NF];
#pragma unroll
        for (int i = 0; i < 4; i++)
            af[i] = *(const bf16x8*)&lA[p][(wm + i * 16 + qr) * 32 + ((quad ^ sw) * 8)];
#pragma unroll
        for (int j = 0; j < NF; j++)
            bfr[j] = *(const bf16x8*)&lB[p][(wn + j * 16 + qr) * 32 + ((quad ^ sw) * 8)];
#pragma unroll
        for (int i = 0; i < 4; i++)
#pragma unroll
            for (int j = 0; j < NF; j++)
                acc[i][j] = __builtin_amdgcn_mfma_f32_16x16x32_bf16(af[i], bfr[j], acc[i][j], 0, 0, 0);
    }

#pragma unroll
    for (int i = 0; i < 4; i++) {
#pragma unroll
        for (int j = 0; j < NF; j++) {
            int col = bn + wn + j * 16 + qr;
            float bv = bias[col];
#pragma unroll
            for (int r = 0; r < 4; r++) {
                int row = bm + wm + i * 16 + quad * 4 + r;
                float val = acc[i][j][r] + bv;
                if (EPI == 0) {
                    int t = row >> 1, b = row & 1;
                    int which = col >> 10;      // 0=q 1=k 2=v
                    int dm = col & 1023;
                    int h = dm >> 6, dh = dm & 63;
                    int bh = b * NH + h;
                    if (which == 0) {
                        outQ[((size_t)bh * T_SEQ + t) * DH + dh] = f2bf(val * SCQ);
                    } else if (which == 1) {
                        outK[((size_t)bh * T_SEQ + t) * DH + dh] = f2bf(val);
                    } else {
                        outV[((size_t)bh * DH + dh) * T_SEQ + t] = f2bf(val);
                    }
                } else {
                    outF[(size_t)row * N + col] = val;
                }
            }
        }
    }
}

// ---------------- flash attention (causal), S^T, static-max, dbuf pipeline ---
// grid (32 bh, 32 y), 256 thr = 4 waves; wave = 16 q-rows; block = 64 q-rows,
// full causal range per block. qt = y<16 ? 31-y : y-16 => with round-robin
// block->CU placement each CU sees qt-sum exactly 62 (y0, y0+8, y0+16, y0+24).
// 4 blocks/CU (LDS 40KB) = 4 independent barrier domains (r7: -4us vs 8-wave).
// T5 setprio(1) around MFMA clusters (blocks at independent phases -> CU
// scheduler can favor the MFMA-entering wave; guide m191 attn +4-7%).
// Per K-tile per wave: 8 QK^T MFMA + 10 PV MFMA (l via ones fragment).
// Epilogue normalizes in-register and writes ctx directly.
// LDS 16B-chunk swizzle: physical = logical ^ (row&7).

__global__ __launch_bounds__(256) void attn_kernel(
    const u16* __restrict__ Qb, const u16* __restrict__ Kb,
    const u16* __restrict__ Vt, u16* __restrict__ ctx)
{
    __shared__ __align__(16) u16 lK[2][64 * 64];    // [key][dh]
    __shared__ __align__(16) u16 lV[2][64 * 64];    // [dh][key]
    __shared__ __align__(16) u16 lP[4][16 * 64];    // per-wave [q][key]

    const int bh   = blockIdx.x;
    const int y    = blockIdx.y;
    const int qt   = (y < 16) ? 31 - y : y - 16;    // long/short pairing for balance
    const int tid  = threadIdx.x;
    const int lane = tid & 63;
    const int wid  = tid >> 6;                      // 0..3
    const int qr   = lane & 15;
    const int quad = lane >> 4;
    const int sw   = qr & 7;

    const int srow = wid * 8 + (lane >> 3);         // 0..31 (per 4KB staging call)
    const int scol = (((lane & 7) ^ ((lane >> 3) & 7))) * 8;

    const u16* Q  = Qb + (size_t)bh * T_SEQ * DH;
    const u16* Kp = Kb + (size_t)bh * T_SEQ * DH;
    const u16* Vp = Vt + (size_t)bh * DH * T_SEQ;
    const int b = bh >> 4, h = bh & 15;

    const int q0 = qt * 64 + wid * 16;              // wave's 16 q-rows

    bf16x8 qf[2];
#pragma unroll
    for (int ks = 0; ks < 2; ks++)
        qf[ks] = *(const bf16x8*)&Q[(size_t)(q0 + qr) * DH + ks * 32 + quad * 8];

    bf16x8 onesf;                                   // constant all-ones A-fragment (l row)
#pragma unroll
    for (int j = 0; j < 8; j++) onesf[j] = (__bf16)1.0f;

    f32x4 o[5];                                     // [4] = l accumulator
#pragma unroll
    for (int f = 0; f < 5; f++) o[f] = f32x4{0.f, 0.f, 0.f, 0.f};

    const int NT = qt + 1;                          // 64-key tiles covering q <= q0max

    // prologue: stage tile 0 into buffer 0 (two 4KB calls per 8KB buffer)
    lds_load16(&lK[0][wid * 512],        &Kp[(size_t)srow * DH + scol]);
    lds_load16(&lK[0][2048 + wid * 512], &Kp[(size_t)(32 + srow) * DH + scol]);
    lds_load16(&lV[0][wid * 512],        &Vp[(size_t)srow * T_SEQ + scol]);
    lds_load16(&lV[0][2048 + wid * 512], &Vp[(size_t)(32 + srow) * T_SEQ + scol]);

    int p = 0;
    for (int kt = 0; kt < NT; kt++, p ^= 1) {
        __syncthreads();                            // tile kt landed; prev reads drained
        if (kt + 1 < NT) {                          // prefetch kt+1 into other buffer
            int nb = p ^ 1;
            lds_load16(&lK[nb][wid * 512],        &Kp[(size_t)((kt + 1) * 64 + srow) * DH + scol]);
            lds_load16(&lK[nb][2048 + wid * 512], &Kp[(size_t)((kt + 1) * 64 + 32 + srow) * DH + scol]);
            lds_load16(&lV[nb][wid * 512],        &Vp[(size_t)srow * T_SEQ + (kt + 1) * 64 + scol]);
            lds_load16(&lV[nb][2048 + wid * 512], &Vp[(size_t)(32 + srow) * T_SEQ + (kt + 1) * 64 + scol]);
        }
        if (kt * 64 > q0 + 15) continue;            // fully masked for this wave

        // S^T = K Q^T : s[fn][r] = S[q = q0+qr][key = kt*64 + fn*16 + quad*4 + r]
        f32x4 s[4];
#pragma unroll
        for (int fn = 0; fn < 4; fn++) s[fn] = f32x4{0.f, 0.f, 0.f, 0.f};
        __builtin_amdgcn_s_setprio(1);
#pragma unroll
        for (int fn = 0; fn < 4; fn++)
#pragma unroll
            for (int ks = 0; ks < 2; ks++) {
                bf16x8 kf = *(const bf16x8*)&lK[p][(fn * 16 + qr) * 64 + (((ks * 4 + quad) ^ sw) * 8)];
                s[fn] = __builtin_amdgcn_mfma_f32_16x16x32_bf16(kf, qf[ks], s[fn], 0, 0, 0);
            }
        __builtin_amdgcn_s_setprio(0);

        // causal mask only near the diagonal (scale already folded into Q)
        if (kt * 64 + 63 > q0) {
            int q = q0 + qr;
#pragma unroll
            for (int fn = 0; fn < 4; fn++) {
                int key = kt * 64 + fn * 16 + quad * 4;
#pragma unroll
                for (int r = 0; r < 4; r++)
                    if (key + r > q) s[fn][r] = -1e30f;
            }
        }

        // static-max softmax: p = exp2(s); C-layout -> A-layout via per-wave LDS
        bf16x8 pf[2];
#pragma unroll
        for (int fn = 0; fn < 4; fn++) {
            float p0 = exp2f(s[fn][0]);
            float p1 = exp2f(s[fn][1]);
            float p2 = exp2f(s[fn][2]);
            float p3 = exp2f(s[fn][3]);
            uint2 w; w.x = pack2(p0, p1); w.y = pack2(p2, p3);
            int phys = ((fn * 2 + (quad >> 1)) ^ sw);
            *(uint2*)&lP[wid][qr * 64 + phys * 8 + (quad & 1) * 4] = w;
        }
#pragma unroll
        for (int ks = 0; ks < 2; ks++)
            pf[ks] = *(const bf16x8*)&lP[wid][qr * 64 + (((ks * 4 + quad) ^ sw) * 8)];

        // O^T += V^T P^T ; f=4 uses the constant ones fragment -> accumulates l
        __builtin_amdgcn_s_setprio(1);
#pragma unroll
        for (int f = 0; f < 5; f++)
#pragma unroll
            for (int ks = 0; ks < 2; ks++) {
                bf16x8 vf = (f == 4) ? onesf
                    : *(const bf16x8*)&lV[p][(f * 16 + qr) * 64 + (((ks * 4 + quad) ^ sw) * 8)];
                o[f] = __builtin_amdgcn_mfma_f32_16x16x32_bf16(vf, pf[ks], o[f], 0, 0, 0);
            }
        __builtin_amdgcn_s_setprio(0);
    }

    // epilogue: normalize in-register, write ctx directly (no merge pass)
    {
        int q = q0 + qr;
        float invl = 1.0f / o[4][0];                // l identical across quad/r
#pragma unroll
        for (int f = 0; f < 4; f++) {
            uint2 w;
            w.x = (uint32_t)f2bf(o[f][0] * invl) | ((uint32_t)f2bf(o[f][1] * invl) << 16);
            w.y = (uint32_t)f2bf(o[f][2] * invl) | ((uint32_t)f2bf(o[f][3] * invl) << 16);
            *(uint2*)&ctx[((size_t)q * BATCH + b) * DMODEL + h * DH + f * 16 + quad * 4] = w;
        }
    }
}

// ---------------- launch ------------------------------------------------------

extern "C" void kernel_launch(void* const* d_in, const int* in_sizes, int n_in,
                              void* d_out, int out_size, void* d_ws, size_t ws_size,
                              hipStream_t stream) {
    const float* x     = (const float*)d_in[0];
    const float* W_qkv = (const float*)d_in[1];
    const float* b_qkv = (const float*)d_in[2];
    const float* W_out = (const float*)d_in[3];
    const float* b_out = (const float*)d_in[4];
    float* out = (float*)d_out;

    char* ws = (char*)d_ws;
    u16* xb     = (u16*)(ws + 0);                    //  8 MB  [4096][1024]
    u16* wqkv_t = (u16*)(ws + (8u  << 20));          //  6 MB  [3072][1024]
    u16* wout_t = (u16*)(ws + (14u << 20));          //  2 MB  [1024][1024]
    u16* Qb     = (u16*)(ws + (16u << 20));          //  8 MB  [32][2048][64]
    u16* Kb     = (u16*)(ws + (24u << 20));          //  8 MB
    u16* Vt     = (u16*)(ws + (32u << 20));          //  8 MB  [32][64][2048]
    u16* ctx    = xb;                                // reuse (xb dead after GEMM1)

    // fused pre-pass: cvt4 (4096 blocks) + both weight transposes (4096 blocks)
    prep_kernel<<<8192, 256, 0, stream>>>(x, xb, W_qkv, wqkv_t, W_out, wout_t);

    // QKV GEMM: NF=6 (BN=192) -> 16x32 = 512 blocks = 2 domains/CU,
    // 24 MFMA/barrier/wave (1.5x NF=4), compute/staging 24/20KB (1.2x)
    gemm_kernel<0, 6><<<dim3(N_QKV / 192, M_ROWS / 128), 256, 0, stream>>>(
        xb, wqkv_t, b_qkv, Qb, Kb, Vt, nullptr, M_ROWS, N_QKV, DMODEL);

    // full-row causal attention: 4-wave blocks, 1024 blocks = 4 domains/CU
    attn_kernel<<<dim3(BATCH * NH, T_SEQ / 64), 256, 0, stream>>>(
        Qb, Kb, Vt, ctx);

    // output projection: NF=2 (BN=64), 512 blocks = 2 blocks/CU
    gemm_kernel<1, 2><<<dim3(DMODEL / 64, M_ROWS / 128), 256, 0, stream>>>(
        ctx, wout_t, b_out, nullptr, nullptr, nullptr, out, M_ROWS, DMODEL, DMODEL);
}

// Round 10
// 176.340 us; speedup vs baseline: 1.0562x; 1.0562x over previous
//
#include <hip/hip_runtime.h>
#include <stdint.h>

#define T_SEQ 2048
#define BATCH 2
#define DMODEL 1024
#define NH 16
#define DH 64
#define M_ROWS (T_SEQ * BATCH)   // 4096
#define N_QKV (3 * DMODEL)       // 3072

typedef unsigned short u16;
using bf16x8 = __attribute__((ext_vector_type(8))) __bf16;
using f32x4  = __attribute__((ext_vector_type(4))) float;

__device__ __forceinline__ u16 f2bf(float f) {
    union { float f; uint32_t u; } v; v.f = f;
    uint32_t r = v.u + 0x7fffu + ((v.u >> 16) & 1u);
    return (u16)(r >> 16);
}

__device__ __forceinline__ uint32_t pack2(float a, float b) {
    union { float f; uint32_t u; } x, y; x.f = a; y.f = b;
    return (x.u >> 16) | (y.u & 0xffff0000u);
}

__device__ __forceinline__ float bf2f(u16 u) {
    union { uint32_t u; float f; } v; v.u = (uint32_t)u << 16;
    return v.f;
}

// async 16B/lane global -> LDS; lds base wave-uniform, lane data lands at +lane*16
__device__ __forceinline__ void lds_load16(void* lds, const void* g) {
    auto lp = (__attribute__((address_space(3))) uint32_t*)(uint32_t)(uintptr_t)lds;
    auto gp = (const __attribute__((address_space(1))) uint32_t*)(uintptr_t)g;
    __builtin_amdgcn_global_load_lds(gp, lp, 16, 0, 0);
}

#define SCQ 0.18033688011112f    // (1/sqrt(64)) * log2(e), folded into Q at GEMM1

// ---------------- pre-pass (fused): x->bf16 + both weight transposes ---------
// blocks [0,4096): cvt4 over x (exactly 4096*256 float4 groups)
// blocks [4096,8192): 32x32 transpose tiles; gx<96 -> W_qkv, else W_out

__global__ void prep_kernel(const float* __restrict__ x, u16* __restrict__ xb,
                            const float* __restrict__ Wq, u16* __restrict__ oq,
                            const float* __restrict__ Wo, u16* __restrict__ oo) {
    __shared__ float t[32][33];
    if (blockIdx.x < 4096) {
        int i = blockIdx.x * 256 + threadIdx.x;
        float4 v = ((const float4*)x)[i];
        union { u16 u[4]; uint2 d; } o;
        o.u[0] = f2bf(v.x); o.u[1] = f2bf(v.y); o.u[2] = f2bf(v.z); o.u[3] = f2bf(v.w);
        ((uint2*)xb)[i] = o.d;
    } else {
        const int R = 1024;
        int bxx = blockIdx.x - 4096;
        int gx = bxx & 127, gy = bxx >> 7;
        const float* in; u16* out; int C, bx;
        if (gx < 96) { in = Wq; out = oq; C = 3072; bx = gx * 32; }
        else         { in = Wo; out = oo; C = 1024; bx = (gx - 96) * 32; }
        int by = gy * 32;
        int tx = threadIdx.x & 31, ty = threadIdx.x >> 5;
#pragma unroll
        for (int rr = 0; rr < 32; rr += 8)
            t[ty + rr][tx] = in[(size_t)(by + ty + rr) * C + bx + tx];
        __syncthreads();
#pragma unroll
        for (int rr = 0; rr < 32; rr += 8)
            out[(size_t)(bx + ty + rr) * R + by + tx] = f2bf(t[tx][ty + rr]);
    }
}

// ---------------- GEMM: A[M][K] bf16 rm, Bt[N][K] bf16 rm --------------------
// BM=128, BN=NF*32, BK=32, 4 waves (2x2), wave tile 64 x NF*16.
// Double-buffered global_load_lds staging: single barrier per K-iter,
// prefetch of k0+32 issued right after the barrier -> drain covered by MFMA.
// XOR chunk-swizzle: phys 16B chunk = logical ^ ((row>>1)&3)
// Session evidence, barrier domains/CU x work-per-barrier (interior optimum):
//   1/CU NF=4 (r1,r2): bad  | 3/CU NF=4 (r0/r8): 45.3us MfmaUtil 22%  <- OPT
//   6/CU NF=2 (r7): 57.0us  | 2/CU NF=6 (r9): 52.7us
// Both directions away from NF=4@3 lose. Template exhausted at ~45us for QKV.

template<int EPI, int NF>
__global__ __launch_bounds__(256) void gemm_kernel(
    const u16* __restrict__ A, const u16* __restrict__ Bt,
    const float* __restrict__ bias,
    u16* __restrict__ outQ, u16* __restrict__ outK, u16* __restrict__ outV,
    float* __restrict__ outF,
    int M, int N, int K)
{
    __shared__ __align__(16) u16 lA[2][128 * 32];
    __shared__ __align__(16) u16 lB[2][NF * 32 * 32];

    const int tid  = threadIdx.x;
    const int bm   = blockIdx.y * 128;
    const int bn   = blockIdx.x * (NF * 32);
    const int lane = tid & 63;
    const int wid  = tid >> 6;
    const int wm   = (wid >> 1) * 64;
    const int wn   = (wid & 1) * (NF * 16);
    const int qr   = lane & 15;
    const int quad = lane >> 4;
    const int r4   = lane >> 2;
    const int c4   = (((lane & 3) ^ ((r4 >> 1) & 3))) * 8;
    const int sw   = (qr >> 1) & 3;

    f32x4 acc[4][NF];
#pragma unroll
    for (int i = 0; i < 4; i++)
#pragma unroll
        for (int j = 0; j < NF; j++) acc[i][j] = f32x4{0.f, 0.f, 0.f, 0.f};

    // prologue: stage k0 = 0 into buffer 0
#pragma unroll
    for (int cc = 0; cc < 2; cc++) {
        int c = wid + cc * 4;
        lds_load16(&lA[0][c * 512], &A[(size_t)(bm + 16 * c + r4) * K + c4]);
    }
#pragma unroll
    for (int c = wid; c < 2 * NF; c += 4)
        lds_load16(&lB[0][c * 512], &Bt[(size_t)(bn + 16 * c + r4) * K + c4]);

    int p = 0;
    for (int k0 = 0; k0 < K; k0 += 32, p ^= 1) {
        __syncthreads();                        // tile k0 landed; prev buffer reads done
        if (k0 + 32 < K) {                      // prefetch next tile into other buffer
            int nb = p ^ 1;
#pragma unroll
            for (int cc = 0; cc < 2; cc++) {
                int c = wid + cc * 4;
                lds_load16(&lA[nb][c * 512], &A[(size_t)(bm + 16 * c + r4) * K + k0 + 32 + c4]);
            }
#pragma unroll
            for (int c = wid; c < 2 * NF; c += 4)
                lds_load16(&lB[nb][c * 512], &Bt[(size_t)(bn + 16 * c + r4) * K + k0 + 32 + c4]);
        }

        bf16x8 af[4], bfr[NF];
#pragma unroll
        for (int i = 0; i < 4; i++)
            af[i] = *(const bf16x8*)&lA[p][(wm + i * 16 + qr) * 32 + ((quad ^ sw) * 8)];
#pragma unroll
        for (int j = 0; j < NF; j++)
            bfr[j] = *(const bf16x8*)&lB[p][(wn + j * 16 + qr) * 32 + ((quad ^ sw) * 8)];
#pragma unroll
        for (int i = 0; i < 4; i++)
#pragma unroll
            for (int j = 0; j < NF; j++)
                acc[i][j] = __builtin_amdgcn_mfma_f32_16x16x32_bf16(af[i], bfr[j], acc[i][j], 0, 0, 0);
    }

#pragma unroll
    for (int i = 0; i < 4; i++) {
#pragma unroll
        for (int j = 0; j < NF; j++) {
            int col = bn + wn + j * 16 + qr;
            float bv = bias[col];
#pragma unroll
            for (int r = 0; r < 4; r++) {
                int row = bm + wm + i * 16 + quad * 4 + r;
                float val = acc[i][j][r] + bv;
                if (EPI == 0) {
                    int t = row >> 1, b = row & 1;
                    int which = col >> 10;      // 0=q 1=k 2=v
                    int dm = col & 1023;
                    int h = dm >> 6, dh = dm & 63;
                    int bh = b * NH + h;
                    if (which == 0) {
                        outQ[((size_t)bh * T_SEQ + t) * DH + dh] = f2bf(val * SCQ);
                    } else if (which == 1) {
                        outK[((size_t)bh * T_SEQ + t) * DH + dh] = f2bf(val);
                    } else {
                        outV[((size_t)bh * DH + dh) * T_SEQ + t] = f2bf(val);
                    }
                } else {
                    outF[(size_t)row * N + col] = val;
                }
            }
        }
    }
}

// ---------------- flash attention (causal), S^T, static-max, dbuf pipeline ---
// grid (32 bh, 32 y), 256 thr = 4 waves; wave = 16 q-rows; block = 64 q-rows,
// full causal range per block. qt = y<16 ? 31-y : y-16 => with round-robin
// block->CU placement each CU sees qt-sum exactly 62 (y0, y0+8, y0+16, y0+24).
// 4 blocks/CU (LDS 40KB) = 4 independent barrier domains (r7: -4us vs 8-wave).
// T5 setprio around MFMA clusters: measured NEUTRAL here (r8->r9 residual
// 133.1 vs 133.5) — kept as harmless.
// Per K-tile per wave: 8 QK^T MFMA + 10 PV MFMA (l via ones fragment).
// Epilogue normalizes in-register and writes ctx directly.
// LDS 16B-chunk swizzle: physical = logical ^ (row&7).

__global__ __launch_bounds__(256) void attn_kernel(
    const u16* __restrict__ Qb, const u16* __restrict__ Kb,
    const u16* __restrict__ Vt, u16* __restrict__ ctx)
{
    __shared__ __align__(16) u16 lK[2][64 * 64];    // [key][dh]
    __shared__ __align__(16) u16 lV[2][64 * 64];    // [dh][key]
    __shared__ __align__(16) u16 lP[4][16 * 64];    // per-wave [q][key]

    const int bh   = blockIdx.x;
    const int y    = blockIdx.y;
    const int qt   = (y < 16) ? 31 - y : y - 16;    // long/short pairing for balance
    const int tid  = threadIdx.x;
    const int lane = tid & 63;
    const int wid  = tid >> 6;                      // 0..3
    const int qr   = lane & 15;
    const int quad = lane >> 4;
    const int sw   = qr & 7;

    const int srow = wid * 8 + (lane >> 3);         // 0..31 (per 4KB staging call)
    const int scol = (((lane & 7) ^ ((lane >> 3) & 7))) * 8;

    const u16* Q  = Qb + (size_t)bh * T_SEQ * DH;
    const u16* Kp = Kb + (size_t)bh * T_SEQ * DH;
    const u16* Vp = Vt + (size_t)bh * DH * T_SEQ;
    const int b = bh >> 4, h = bh & 15;

    const int q0 = qt * 64 + wid * 16;              // wave's 16 q-rows

    bf16x8 qf[2];
#pragma unroll
    for (int ks = 0; ks < 2; ks++)
        qf[ks] = *(const bf16x8*)&Q[(size_t)(q0 + qr) * DH + ks * 32 + quad * 8];

    bf16x8 onesf;                                   // constant all-ones A-fragment (l row)
#pragma unroll
    for (int j = 0; j < 8; j++) onesf[j] = (__bf16)1.0f;

    f32x4 o[5];                                     // [4] = l accumulator
#pragma unroll
    for (int f = 0; f < 5; f++) o[f] = f32x4{0.f, 0.f, 0.f, 0.f};

    const int NT = qt + 1;                          // 64-key tiles covering q <= q0max

    // prologue: stage tile 0 into buffer 0 (two 4KB calls per 8KB buffer)
    lds_load16(&lK[0][wid * 512],        &Kp[(size_t)srow * DH + scol]);
    lds_load16(&lK[0][2048 + wid * 512], &Kp[(size_t)(32 + srow) * DH + scol]);
    lds_load16(&lV[0][wid * 512],        &Vp[(size_t)srow * T_SEQ + scol]);
    lds_load16(&lV[0][2048 + wid * 512], &Vp[(size_t)(32 + srow) * T_SEQ + scol]);

    int p = 0;
    for (int kt = 0; kt < NT; kt++, p ^= 1) {
        __syncthreads();                            // tile kt landed; prev reads drained
        if (kt + 1 < NT) {                          // prefetch kt+1 into other buffer
            int nb = p ^ 1;
            lds_load16(&lK[nb][wid * 512],        &Kp[(size_t)((kt + 1) * 64 + srow) * DH + scol]);
            lds_load16(&lK[nb][2048 + wid * 512], &Kp[(size_t)((kt + 1) * 64 + 32 + srow) * DH + scol]);
            lds_load16(&lV[nb][wid * 512],        &Vp[(size_t)srow * T_SEQ + (kt + 1) * 64 + scol]);
            lds_load16(&lV[nb][2048 + wid * 512], &Vp[(size_t)(32 + srow) * T_SEQ + (kt + 1) * 64 + scol]);
        }
        if (kt * 64 > q0 + 15) continue;            // fully masked for this wave

        // S^T = K Q^T : s[fn][r] = S[q = q0+qr][key = kt*64 + fn*16 + quad*4 + r]
        f32x4 s[4];
#pragma unroll
        for (int fn = 0; fn < 4; fn++) s[fn] = f32x4{0.f, 0.f, 0.f, 0.f};
        __builtin_amdgcn_s_setprio(1);
#pragma unroll
        for (int fn = 0; fn < 4; fn++)
#pragma unroll
            for (int ks = 0; ks < 2; ks++) {
                bf16x8 kf = *(const bf16x8*)&lK[p][(fn * 16 + qr) * 64 + (((ks * 4 + quad) ^ sw) * 8)];
                s[fn] = __builtin_amdgcn_mfma_f32_16x16x32_bf16(kf, qf[ks], s[fn], 0, 0, 0);
            }
        __builtin_amdgcn_s_setprio(0);

        // causal mask only near the diagonal (scale already folded into Q)
        if (kt * 64 + 63 > q0) {
            int q = q0 + qr;
#pragma unroll
            for (int fn = 0; fn < 4; fn++) {
                int key = kt * 64 + fn * 16 + quad * 4;
#pragma unroll
                for (int r = 0; r < 4; r++)
                    if (key + r > q) s[fn][r] = -1e30f;
            }
        }

        // static-max softmax: p = exp2(s); C-layout -> A-layout via per-wave LDS
        bf16x8 pf[2];
#pragma unroll
        for (int fn = 0; fn < 4; fn++) {
            float p0 = exp2f(s[fn][0]);
            float p1 = exp2f(s[fn][1]);
            float p2 = exp2f(s[fn][2]);
            float p3 = exp2f(s[fn][3]);
            uint2 w; w.x = pack2(p0, p1); w.y = pack2(p2, p3);
            int phys = ((fn * 2 + (quad >> 1)) ^ sw);
            *(uint2*)&lP[wid][qr * 64 + phys * 8 + (quad & 1) * 4] = w;
        }
#pragma unroll
        for (int ks = 0; ks < 2; ks++)
            pf[ks] = *(const bf16x8*)&lP[wid][qr * 64 + (((ks * 4 + quad) ^ sw) * 8)];

        // O^T += V^T P^T ; f=4 uses the constant ones fragment -> accumulates l
        __builtin_amdgcn_s_setprio(1);
#pragma unroll
        for (int f = 0; f < 5; f++)
#pragma unroll
            for (int ks = 0; ks < 2; ks++) {
                bf16x8 vf = (f == 4) ? onesf
                    : *(const bf16x8*)&lV[p][(f * 16 + qr) * 64 + (((ks * 4 + quad) ^ sw) * 8)];
                o[f] = __builtin_amdgcn_mfma_f32_16x16x32_bf16(vf, pf[ks], o[f], 0, 0, 0);
            }
        __builtin_amdgcn_s_setprio(0);
    }

    // epilogue: normalize in-register, write ctx directly (no merge pass)
    {
        int q = q0 + qr;
        float invl = 1.0f / o[4][0];                // l identical across quad/r
#pragma unroll
        for (int f = 0; f < 4; f++) {
            uint2 w;
            w.x = (uint32_t)f2bf(o[f][0] * invl) | ((uint32_t)f2bf(o[f][1] * invl) << 16);
            w.y = (uint32_t)f2bf(o[f][2] * invl) | ((uint32_t)f2bf(o[f][3] * invl) << 16);
            *(uint2*)&ctx[((size_t)q * BATCH + b) * DMODEL + h * DH + f * 16 + quad * 4] = w;
        }
    }
}

// ---------------- launch ------------------------------------------------------

extern "C" void kernel_launch(void* const* d_in, const int* in_sizes, int n_in,
                              void* d_out, int out_size, void* d_ws, size_t ws_size,
                              hipStream_t stream) {
    const float* x     = (const float*)d_in[0];
    const float* W_qkv = (const float*)d_in[1];
    const float* b_qkv = (const float*)d_in[2];
    const float* W_out = (const float*)d_in[3];
    const float* b_out = (const float*)d_in[4];
    float* out = (float*)d_out;

    char* ws = (char*)d_ws;
    u16* xb     = (u16*)(ws + 0);                    //  8 MB  [4096][1024]
    u16* wqkv_t = (u16*)(ws + (8u  << 20));          //  6 MB  [3072][1024]
    u16* wout_t = (u16*)(ws + (14u << 20));          //  2 MB  [1024][1024]
    u16* Qb     = (u16*)(ws + (16u << 20));          //  8 MB  [32][2048][64]
    u16* Kb     = (u16*)(ws + (24u << 20));          //  8 MB
    u16* Vt     = (u16*)(ws + (32u << 20));          //  8 MB  [32][64][2048]
    u16* ctx    = xb;                                // reuse (xb dead after GEMM1)

    // fused pre-pass: cvt4 (4096 blocks) + both weight transposes (4096 blocks)
    prep_kernel<<<8192, 256, 0, stream>>>(x, xb, W_qkv, wqkv_t, W_out, wout_t);

    // QKV GEMM: NF=4 (BN=128) -> 24x32 = 768 blocks = 3 barrier domains/CU (optimum)
    gemm_kernel<0, 4><<<dim3(N_QKV / 128, M_ROWS / 128), 256, 0, stream>>>(
        xb, wqkv_t, b_qkv, Qb, Kb, Vt, nullptr, M_ROWS, N_QKV, DMODEL);

    // full-row causal attention: 4-wave blocks, 1024 blocks = 4 domains/CU
    attn_kernel<<<dim3(BATCH * NH, T_SEQ / 64), 256, 0, stream>>>(
        Qb, Kb, Vt, ctx);

    // output projection: NF=2 (BN=64), 512 blocks = 2 blocks/CU
    gemm_kernel<1, 2><<<dim3(DMODEL / 64, M_ROWS / 128), 256, 0, stream>>>(
        ctx, wout_t, b_out, nullptr, nullptr, nullptr, out, M_ROWS, DMODEL, DMODEL);
}